// Round 1
// baseline (699.055 us; speedup 1.0000x reference)
//
#include <hip/hip_runtime.h>
#include <hip/hip_bf16.h>

// Problem constants: B=4, C=128, Cq=16, W=H=64, N=4096.
// ws layout (floats): q[4][16][4096] @0, k[4][16][4096] @262144, v[4][128][4096] @524288
// d_out: out[4][128][4096] (2097152 floats) then attention[4][4096][4096] (67108864 floats)

// ---------------- Kernel 1: QKV projections ----------------
// grid (64 n-tiles, 4 b), 512 threads. x-tile staged in LDS; weight rows are
// wave-uniform (og = t>>6 readfirstlane'd) so they compile to s_loads.
__global__ __launch_bounds__(512, 2) void qkv_kernel(
    const float* __restrict__ x,
    const float* __restrict__ wq, const float* __restrict__ bq,
    const float* __restrict__ wk, const float* __restrict__ bk,
    const float* __restrict__ wv, const float* __restrict__ bv,
    float* __restrict__ qo, float* __restrict__ ko, float* __restrict__ vo) {
  __shared__ float xs[128 * 64];
  const int nt = blockIdx.x, b = blockIdx.y;
  const int n0 = nt * 64;
  const float* xb = x + (size_t)b * 524288 + n0;
  for (int idx = threadIdx.x; idx < 8192; idx += 512) {
    int c = idx >> 6, n = idx & 63;
    xs[idx] = xb[(size_t)c * 4096 + n];
  }
  __syncthreads();
  const int n = threadIdx.x & 63;
  const int og = __builtin_amdgcn_readfirstlane((int)(threadIdx.x >> 6)); // 0..7, wave-uniform
  float acc[20];
#pragma unroll
  for (int i = 0; i < 20; i++) {
    int o = og + 8 * i;
    acc[i] = (i < 2) ? bq[o] : (i < 4) ? bk[o - 16] : bv[o - 32];
  }
#pragma unroll 4
  for (int c = 0; c < 128; c++) {
    float xr = xs[c * 64 + n];
#pragma unroll
    for (int i = 0; i < 20; i++) {
      int o = og + 8 * i;
      const float* wr = (i < 2) ? (wq + o * 128)
                      : (i < 4) ? (wk + (o - 16) * 128)
                                : (wv + (o - 32) * 128);
      acc[i] += wr[c] * xr;
    }
  }
#pragma unroll
  for (int i = 0; i < 20; i++) {
    int o = og + 8 * i;
    if (i < 2)      qo[(size_t)b * 65536  + (size_t)o        * 4096 + n0 + n] = acc[i];
    else if (i < 4) ko[(size_t)b * 65536  + (size_t)(o - 16) * 4096 + n0 + n] = acc[i];
    else            vo[(size_t)b * 524288 + (size_t)(o - 32) * 4096 + n0 + n] = acc[i];
  }
}

// ---------------- Kernel 2: energy + softmax + attention write ----------------
// 512 blocks x 256 threads. Block = (b, rb, half): 32 rows, M=(rb+1)*64 valid cols.
// Wave owns 8 rows. Two passes: (A) sum of exp(e) per row (no max-sub; |e| small,
// fp32-safe), (B) recompute e, write exp(e)*inv_sum. Masked tail written as zeros.
__global__ __launch_bounds__(256, 2) void attn_kernel(
    const float* __restrict__ qo, const float* __restrict__ ko,
    float* __restrict__ attn) {
  const int bx = blockIdx.x;            // 0..511
  const int b = bx & 3;
  const int v_ = bx >> 2;               // 0..127
  const int half = v_ & 1;
  const int u = v_ >> 1;                // 0..63
  const int rb = (u < 32) ? u : 95 - u; // CU-mate load balancing
  const int M = (rb + 1) * 64;
  const int lane = threadIdx.x & 63;
  const int wave = __builtin_amdgcn_readfirstlane((int)(threadIdx.x >> 6));
  const int nbase = rb * 64 + half * 32 + wave * 8;
  const float* qb = qo + (size_t)b * 65536;
  const float* kb = ko + (size_t)b * 65536;
  float* ab = attn + (size_t)b * 16777216;

  float qv[8][16];
#pragma unroll
  for (int r = 0; r < 8; r++)
#pragma unroll
    for (int d = 0; d < 16; d++)
      qv[r][d] = qb[d * 4096 + nbase + r];

  float sume[8];
#pragma unroll
  for (int r = 0; r < 8; r++) sume[r] = 0.f;

  for (int m0 = 0; m0 < M; m0 += 64) {
    float kreg[16];
#pragma unroll
    for (int d = 0; d < 16; d++) kreg[d] = kb[d * 4096 + m0 + lane];
#pragma unroll
    for (int r = 0; r < 8; r++) {
      float e = 0.f;
#pragma unroll
      for (int d = 0; d < 16; d++) e += qv[r][d] * kreg[d];
      sume[r] += __expf(e);
    }
  }

  float inv[8];
#pragma unroll
  for (int r = 0; r < 8; r++) {
    float s = sume[r];
#pragma unroll
    for (int off = 32; off > 0; off >>= 1) s += __shfl_xor(s, off, 64);
    inv[r] = 1.0f / s;
  }

  for (int m0 = 0; m0 < M; m0 += 64) {
    float kreg[16];
#pragma unroll
    for (int d = 0; d < 16; d++) kreg[d] = kb[d * 4096 + m0 + lane];
#pragma unroll
    for (int r = 0; r < 8; r++) {
      float e = 0.f;
#pragma unroll
      for (int d = 0; d < 16; d++) e += qv[r][d] * kreg[d];
      ab[(size_t)(nbase + r) * 4096 + m0 + lane] = __expf(e) * inv[r];
    }
  }

  // zero-fill masked region (harness poisons d_out every launch)
  const int Z4 = (4096 - M) >> 2;
#pragma unroll
  for (int r = 0; r < 8; r++) {
    float4* dst = (float4*)(ab + (size_t)(nbase + r) * 4096 + M);
    for (int i4 = lane; i4 < Z4; i4 += 64)
      dst[i4] = make_float4(0.f, 0.f, 0.f, 0.f);
  }
}

// ---------------- Kernel 3: out = gamma * (V . attn^T) + x ----------------
// 512 blocks x 256 threads. Block = (nt, b, ct): 64c x 64n tile, K=(nt+1)*64
// (uniform within aligned n-tile thanks to block-causal mask). LDS tiles stored
// k-major ([32][68] padded) so the inner loop is 2x ds_read_b128 + 16 v_fma.
__global__ __launch_bounds__(256, 2) void out_kernel(
    const float* __restrict__ vo, const float* __restrict__ attn,
    const float* __restrict__ x, const float* __restrict__ g,
    float* __restrict__ out) {
  __shared__ float As[32 * 68];
  __shared__ float Vs[32 * 68];
  const int bx = blockIdx.x;            // 0..511
  const int ct = bx & 1;
  const int b = (bx >> 1) & 3;
  const int u = bx >> 3;                // 0..63
  const int nt = (u < 32) ? u : 95 - u; // CU-mate load balancing
  const int n0 = nt * 64, c0 = ct * 64;
  const int K = (nt + 1) * 64;
  const int t = threadIdx.x;
  const int tn = t & 15, tc = t >> 4;
  const int lm = t & 31, lr = t >> 5;   // staging map: k-col lm, row lr+8p
  const float* ap = attn + (size_t)b * 16777216 + (size_t)n0 * 4096;
  const float* vp = vo + (size_t)b * 524288 + (size_t)c0 * 4096;

  float acc[4][4];
#pragma unroll
  for (int i = 0; i < 4; i++)
#pragma unroll
    for (int j = 0; j < 4; j++) acc[i][j] = 0.f;

  for (int kb = 0; kb < K; kb += 32) {
#pragma unroll
    for (int p = 0; p < 8; p++) {
      int row = lr + p * 8;
      As[lm * 68 + row] = ap[(size_t)row * 4096 + kb + lm];
      Vs[lm * 68 + row] = vp[(size_t)row * 4096 + kb + lm];
    }
    __syncthreads();
#pragma unroll
    for (int kk = 0; kk < 32; kk++) {
      float4 av = *(const float4*)&As[kk * 68 + 4 * tn];
      float4 vv = *(const float4*)&Vs[kk * 68 + 4 * tc];
      acc[0][0] += vv.x * av.x; acc[0][1] += vv.x * av.y; acc[0][2] += vv.x * av.z; acc[0][3] += vv.x * av.w;
      acc[1][0] += vv.y * av.x; acc[1][1] += vv.y * av.y; acc[1][2] += vv.y * av.z; acc[1][3] += vv.y * av.w;
      acc[2][0] += vv.z * av.x; acc[2][1] += vv.z * av.y; acc[2][2] += vv.z * av.z; acc[2][3] += vv.z * av.w;
      acc[3][0] += vv.w * av.x; acc[3][1] += vv.w * av.y; acc[3][2] += vv.w * av.z; acc[3][3] += vv.w * av.w;
    }
    __syncthreads();
  }

  const float gamma = g[0];
#pragma unroll
  for (int i = 0; i < 4; i++) {
    int c = c0 + 4 * tc + i;
    size_t off = (size_t)b * 524288 + (size_t)c * 4096 + n0 + 4 * tn;
    float4 xr = *(const float4*)&x[off];
    float4 o;
    o.x = gamma * acc[i][0] + xr.x;
    o.y = gamma * acc[i][1] + xr.y;
    o.z = gamma * acc[i][2] + xr.z;
    o.w = gamma * acc[i][3] + xr.w;
    *(float4*)&out[off] = o;
  }
}

extern "C" void kernel_launch(void* const* d_in, const int* in_sizes, int n_in,
                              void* d_out, int out_size, void* d_ws, size_t ws_size,
                              hipStream_t stream) {
  const float* x  = (const float*)d_in[0];
  const float* wq = (const float*)d_in[1];
  const float* bq = (const float*)d_in[2];
  const float* wk = (const float*)d_in[3];
  const float* bk = (const float*)d_in[4];
  const float* wv = (const float*)d_in[5];
  const float* bv = (const float*)d_in[6];
  const float* gm = (const float*)d_in[7];
  float* out  = (float*)d_out;
  float* attn = out + 2097152;   // output 1: attention [4][4096][4096]
  float* qws = (float*)d_ws;     // [4][16][4096]
  float* kws = qws + 262144;     // [4][16][4096]
  float* vws = qws + 524288;     // [4][128][4096]

  qkv_kernel<<<dim3(64, 4), 512, 0, stream>>>(x, wq, bq, wk, bk, wv, bv, qws, kws, vws);
  attn_kernel<<<dim3(512), 256, 0, stream>>>(qws, kws, attn);
  out_kernel<<<dim3(512), 256, 0, stream>>>(vws, attn, x, gm, out);
}

// Round 2
// 502.034 us; speedup vs baseline: 1.3924x; 1.3924x over previous
//
#include <hip/hip_runtime.h>
#include <hip/hip_bf16.h>

// Problem constants: B=4, C=128, Cq=16, W=H=64, N=4096.
// ws layout: q fp32 [4][16][4096] @float0, k fp32 [4][16][4096] @float262144,
//            v BF16 [4][128][4096] @float524288 (2M ushorts = 4 MB)
// d_out: out[4][128][4096] fp32, then attention[4][4096][4096] fp32

typedef __attribute__((ext_vector_type(8))) short short8;
typedef __attribute__((ext_vector_type(16))) float float16;

__device__ __forceinline__ ushort f2bf(float f) {
  union { float f; uint u; } v; v.f = f;
  return (ushort)((v.u + 0x7FFFu + ((v.u >> 16) & 1u)) >> 16);  // RNE
}
__device__ __forceinline__ uint pk2(float a, float b) {
  return (uint)f2bf(a) | ((uint)f2bf(b) << 16);
}

// ---------------- Kernel 1: QKV projections ----------------
// grid (64 n-tiles, 4 b), 512 threads. x-tile staged in LDS; weight rows are
// wave-uniform so they compile to s_loads. V written as bf16 (only the out-GEMM
// consumes V, and it computes in bf16 MFMA).
__global__ __launch_bounds__(512, 2) void qkv_kernel(
    const float* __restrict__ x,
    const float* __restrict__ wq, const float* __restrict__ bq,
    const float* __restrict__ wk, const float* __restrict__ bk,
    const float* __restrict__ wv, const float* __restrict__ bv,
    float* __restrict__ qo, float* __restrict__ ko, ushort* __restrict__ vo) {
  __shared__ float xs[128 * 64];
  const int nt = blockIdx.x, b = blockIdx.y;
  const int n0 = nt * 64;
  const float* xb = x + (size_t)b * 524288 + n0;
  for (int idx = threadIdx.x; idx < 8192; idx += 512) {
    int c = idx >> 6, n = idx & 63;
    xs[idx] = xb[(size_t)c * 4096 + n];
  }
  __syncthreads();
  const int n = threadIdx.x & 63;
  const int og = __builtin_amdgcn_readfirstlane((int)(threadIdx.x >> 6)); // 0..7
  float acc[20];
#pragma unroll
  for (int i = 0; i < 20; i++) {
    int o = og + 8 * i;
    acc[i] = (i < 2) ? bq[o] : (i < 4) ? bk[o - 16] : bv[o - 32];
  }
#pragma unroll 4
  for (int c = 0; c < 128; c++) {
    float xr = xs[c * 64 + n];
#pragma unroll
    for (int i = 0; i < 20; i++) {
      int o = og + 8 * i;
      const float* wr = (i < 2) ? (wq + o * 128)
                      : (i < 4) ? (wk + (o - 16) * 128)
                                : (wv + (o - 32) * 128);
      acc[i] += wr[c] * xr;
    }
  }
#pragma unroll
  for (int i = 0; i < 20; i++) {
    int o = og + 8 * i;
    if (i < 2)      qo[(size_t)b * 65536  + (size_t)o        * 4096 + n0 + n] = acc[i];
    else if (i < 4) ko[(size_t)b * 65536  + (size_t)(o - 16) * 4096 + n0 + n] = acc[i];
    else            vo[(size_t)b * 524288 + (size_t)(o - 32) * 4096 + n0 + n] = f2bf(acc[i]);
  }
}

// ---------------- Kernel 2: energy + softmax + attention write ----------------
// (unchanged from round 1 — correct; re-profile now that out_kernel shrinks)
__global__ __launch_bounds__(256, 2) void attn_kernel(
    const float* __restrict__ qo, const float* __restrict__ ko,
    float* __restrict__ attn) {
  const int bx = blockIdx.x;            // 0..511
  const int b = bx & 3;
  const int v_ = bx >> 2;               // 0..127
  const int half = v_ & 1;
  const int u = v_ >> 1;                // 0..63
  const int rb = (u < 32) ? u : 95 - u; // CU-mate load balancing
  const int M = (rb + 1) * 64;
  const int lane = threadIdx.x & 63;
  const int wave = __builtin_amdgcn_readfirstlane((int)(threadIdx.x >> 6));
  const int nbase = rb * 64 + half * 32 + wave * 8;
  const float* qb = qo + (size_t)b * 65536;
  const float* kb = ko + (size_t)b * 65536;
  float* ab = attn + (size_t)b * 16777216;

  float qv[8][16];
#pragma unroll
  for (int r = 0; r < 8; r++)
#pragma unroll
    for (int d = 0; d < 16; d++)
      qv[r][d] = qb[d * 4096 + nbase + r];

  float sume[8];
#pragma unroll
  for (int r = 0; r < 8; r++) sume[r] = 0.f;

  for (int m0 = 0; m0 < M; m0 += 64) {
    float kreg[16];
#pragma unroll
    for (int d = 0; d < 16; d++) kreg[d] = kb[d * 4096 + m0 + lane];
#pragma unroll
    for (int r = 0; r < 8; r++) {
      float e = 0.f;
#pragma unroll
      for (int d = 0; d < 16; d++) e += qv[r][d] * kreg[d];
      sume[r] += __expf(e);
    }
  }

  float inv[8];
#pragma unroll
  for (int r = 0; r < 8; r++) {
    float s = sume[r];
#pragma unroll
    for (int off = 32; off > 0; off >>= 1) s += __shfl_xor(s, off, 64);
    inv[r] = 1.0f / s;
  }

  for (int m0 = 0; m0 < M; m0 += 64) {
    float kreg[16];
#pragma unroll
    for (int d = 0; d < 16; d++) kreg[d] = kb[d * 4096 + m0 + lane];
#pragma unroll
    for (int r = 0; r < 8; r++) {
      float e = 0.f;
#pragma unroll
      for (int d = 0; d < 16; d++) e += qv[r][d] * kreg[d];
      ab[(size_t)(nbase + r) * 4096 + m0 + lane] = __expf(e) * inv[r];
    }
  }

  const int Z4 = (4096 - M) >> 2;
#pragma unroll
  for (int r = 0; r < 8; r++) {
    float4* dst = (float4*)(ab + (size_t)(nbase + r) * 4096 + M);
    for (int i4 = lane; i4 < Z4; i4 += 64)
      dst[i4] = make_float4(0.f, 0.f, 0.f, 0.f);
  }
}

// ---------------- Kernel 3: out = gamma * (V . attn^T) + x  (bf16 MFMA) ----
// grid (64 nt, 4 b) = 256 blocks, 256 thr (4 waves). Tile: 128c x 64n,
// K=(nt+1)*64 (masked attn tail is zero, so fixed K per n-tile is exact).
// Wave w = c-quadrant w (32 rows of V) x both 32-wide n-halves:
// 2x mfma_f32_32x32x16_bf16 per k-step, A=V-frag, B=P^T-frag.
// LDS pitch 72 bf16 (144 B): frag reads are 2-way bank-aliased only (free).
__global__ __launch_bounds__(256, 2) void out_kernel(
    const ushort* __restrict__ vws, const float* __restrict__ attn,
    const float* __restrict__ x, const float* __restrict__ g,
    float* __restrict__ out) {
  __shared__ __align__(16) ushort Ps[64 * 72];
  __shared__ __align__(16) ushort Vs[128 * 72];
  const int nt = blockIdx.x, b = blockIdx.y;
  const int n0 = nt * 64;
  const int K = (nt + 1) * 64;
  const int t = threadIdx.x;
  const int lane = t & 63;
  const int wave = __builtin_amdgcn_readfirstlane(t >> 6); // c-quadrant
  const int half = lane >> 5;
  const int l31 = lane & 31;
  const float* ap = attn + (size_t)b * 16777216 + (size_t)n0 * 4096;
  const ushort* vp = vws + (size_t)b * 524288;

  float16 acc0, acc1;
#pragma unroll
  for (int i = 0; i < 16; i++) { acc0[i] = 0.f; acc1[i] = 0.f; }

  const int pr = t >> 2, pc = (t & 3) * 16;  // attn staging: 16 floats/thread
  const int vr = t >> 1, vc = (t & 1) * 32;  // V staging: 32 bf16/thread

  for (int kb = 0; kb < K; kb += 64) {
    const float* src = ap + (size_t)pr * 4096 + kb + pc;
    float4 f0 = *(const float4*)(src);
    float4 f1 = *(const float4*)(src + 4);
    float4 f2 = *(const float4*)(src + 8);
    float4 f3 = *(const float4*)(src + 12);
    const uint4* vsrc = (const uint4*)(vp + (size_t)vr * 4096 + kb + vc);
    uint4 v0 = vsrc[0], v1 = vsrc[1], v2 = vsrc[2], v3 = vsrc[3];
    __syncthreads();  // previous iter's frag reads done before overwrite
    uint4 p0, p1;
    p0.x = pk2(f0.x, f0.y); p0.y = pk2(f0.z, f0.w);
    p0.z = pk2(f1.x, f1.y); p0.w = pk2(f1.z, f1.w);
    p1.x = pk2(f2.x, f2.y); p1.y = pk2(f2.z, f2.w);
    p1.z = pk2(f3.x, f3.y); p1.w = pk2(f3.z, f3.w);
    *(uint4*)(Ps + pr * 72 + pc) = p0;
    *(uint4*)(Ps + pr * 72 + pc + 8) = p1;
    uint4* dv = (uint4*)(Vs + vr * 72 + vc);
    dv[0] = v0; dv[1] = v1; dv[2] = v2; dv[3] = v3;
    __syncthreads();
#pragma unroll
    for (int kk = 0; kk < 4; kk++) {
      const int ko = kk * 16 + half * 8;
      short8 a  = *(const short8*)(Vs + (wave * 32 + l31) * 72 + ko);
      short8 b0 = *(const short8*)(Ps + l31 * 72 + ko);
      short8 b1 = *(const short8*)(Ps + (32 + l31) * 72 + ko);
      acc0 = __builtin_amdgcn_mfma_f32_32x32x16_bf16(a, b0, acc0, 0, 0, 0);
      acc1 = __builtin_amdgcn_mfma_f32_32x32x16_bf16(a, b1, acc1, 0, 0, 0);
    }
  }

  const float gamma = g[0];
#pragma unroll
  for (int nq = 0; nq < 2; nq++) {
    const float16& a = nq ? acc1 : acc0;
#pragma unroll
    for (int reg = 0; reg < 16; reg++) {
      int row = (reg & 3) + 8 * (reg >> 2) + 4 * half;  // C/D: row map
      int c = wave * 32 + row;
      int n = n0 + nq * 32 + l31;                        // C/D: col = lane&31
      size_t off = (size_t)b * 524288 + (size_t)c * 4096 + n;
      out[off] = gamma * a[reg] + x[off];
    }
  }
}

extern "C" void kernel_launch(void* const* d_in, const int* in_sizes, int n_in,
                              void* d_out, int out_size, void* d_ws, size_t ws_size,
                              hipStream_t stream) {
  const float* x  = (const float*)d_in[0];
  const float* wq = (const float*)d_in[1];
  const float* bq = (const float*)d_in[2];
  const float* wk = (const float*)d_in[3];
  const float* bk = (const float*)d_in[4];
  const float* wv = (const float*)d_in[5];
  const float* bv = (const float*)d_in[6];
  const float* gm = (const float*)d_in[7];
  float* out  = (float*)d_out;
  float* attn = out + 2097152;          // output 1: attention [4][4096][4096]
  float* qws = (float*)d_ws;            // fp32 [4][16][4096]
  float* kws = qws + 262144;            // fp32 [4][16][4096]
  ushort* vws = (ushort*)(qws + 524288); // bf16 [4][128][4096]

  qkv_kernel<<<dim3(64, 4), 512, 0, stream>>>(x, wq, bq, wk, bk, wv, bv, qws, kws, vws);
  attn_kernel<<<dim3(512), 256, 0, stream>>>(qws, kws, attn);
  out_kernel<<<dim3(64, 4), 256, 0, stream>>>(vws, attn, x, gm, out);
}

// Round 3
// 438.355 us; speedup vs baseline: 1.5947x; 1.1453x over previous
//
#include <hip/hip_runtime.h>
#include <hip/hip_bf16.h>

// Problem constants: B=4, C=128, Cq=16, W=H=64, N=4096.
// ws layout: q fp32 [4][16][4096] @float0, k fp32 [4][16][4096] @float262144,
//            v BF16 [4][128][4096] @float524288 (2M ushorts = 4 MB)
// d_out: out[4][128][4096] fp32, then attention[4][4096][4096] fp32

typedef __attribute__((ext_vector_type(8))) short short8;
typedef __attribute__((ext_vector_type(16))) float float16;

__device__ __forceinline__ ushort f2bf(float f) {
  union { float f; uint u; } v; v.f = f;
  return (ushort)((v.u + 0x7FFFu + ((v.u >> 16) & 1u)) >> 16);  // RNE
}

// ---------------- Kernel 1: QKV projections ----------------
// grid (64 n-tiles, 4 b), 512 threads. x-tile staged in LDS; weight rows are
// wave-uniform so they compile to s_loads. V written as bf16 (only the PV MFMA
// consumes V).
__global__ __launch_bounds__(512, 2) void qkv_kernel(
    const float* __restrict__ x,
    const float* __restrict__ wq, const float* __restrict__ bq,
    const float* __restrict__ wk, const float* __restrict__ bk,
    const float* __restrict__ wv, const float* __restrict__ bv,
    float* __restrict__ qo, float* __restrict__ ko, ushort* __restrict__ vo) {
  __shared__ float xs[128 * 64];
  const int nt = blockIdx.x, b = blockIdx.y;
  const int n0 = nt * 64;
  const float* xb = x + (size_t)b * 524288 + n0;
  for (int idx = threadIdx.x; idx < 8192; idx += 512) {
    int c = idx >> 6, n = idx & 63;
    xs[idx] = xb[(size_t)c * 4096 + n];
  }
  __syncthreads();
  const int n = threadIdx.x & 63;
  const int og = __builtin_amdgcn_readfirstlane((int)(threadIdx.x >> 6)); // 0..7
  float acc[20];
#pragma unroll
  for (int i = 0; i < 20; i++) {
    int o = og + 8 * i;
    acc[i] = (i < 2) ? bq[o] : (i < 4) ? bk[o - 16] : bv[o - 32];
  }
#pragma unroll 4
  for (int c = 0; c < 128; c++) {
    float xr = xs[c * 64 + n];
#pragma unroll
    for (int i = 0; i < 20; i++) {
      int o = og + 8 * i;
      const float* wr = (i < 2) ? (wq + o * 128)
                      : (i < 4) ? (wk + (o - 16) * 128)
                                : (wv + (o - 32) * 128);
      acc[i] += wr[c] * xr;
    }
  }
#pragma unroll
  for (int i = 0; i < 20; i++) {
    int o = og + 8 * i;
    if (i < 2)      qo[(size_t)b * 65536  + (size_t)o        * 4096 + n0 + n] = acc[i];
    else if (i < 4) ko[(size_t)b * 65536  + (size_t)(o - 16) * 4096 + n0 + n] = acc[i];
    else            vo[(size_t)b * 524288 + (size_t)(o - 32) * 4096 + n0 + n] = f2bf(acc[i]);
  }
}

// ---------------- Kernel 2: fused energy + softmax + attn-write + PV ----------
// 512 blocks x 256 thr (4 waves). Block = (b, rb, half): 32 rows n, M=(rb+1)*64
// valid cols. Pairing rb = (u<32)?u:95-u balances co-resident CU-mates (work
// sums to 65 strips/pair).
// Phase 1: rowwise sum of exp(e) (wave = 8 rows, lane = m; k strips in regs).
// Phase 2: per 64-m strip: recompute e -> p = exp(e)*inv; write p to attn AND
// to a bf16 LDS P-tile [32n][72-pitch]; then MFMA out[128c][32n] += V.P^T with
// A = V-frag straight from global (L2-hot), B = P-frag from LDS. Layouts are
// identical to the verified round-2 out_kernel. Double-buffered P-tile ->
// single barrier per strip. Epilogue: zero-fill masked attn + out = g*acc + x.
__global__ __launch_bounds__(256, 2) void fused_attn_kernel(
    const float* __restrict__ qo, const float* __restrict__ ko,
    const ushort* __restrict__ vws, const float* __restrict__ x,
    const float* __restrict__ g,
    float* __restrict__ attn, float* __restrict__ out) {
  __shared__ __align__(16) ushort Ps[2][32 * 72];
  const int bx = blockIdx.x;            // 0..511
  const int b = bx & 3;
  const int v_ = bx >> 2;               // 0..127
  const int half = v_ & 1;
  const int u = v_ >> 1;                // 0..63
  const int rb = (u < 32) ? u : 95 - u; // CU-mate load balancing
  const int S = rb + 1;                 // number of 64-wide m strips
  const int M = S * 64;
  const int lane = threadIdx.x & 63;
  const int wave = __builtin_amdgcn_readfirstlane((int)(threadIdx.x >> 6));
  const int nblk = rb * 64 + half * 32; // block's first row
  const int nbase = nblk + wave * 8;    // wave's first row
  const int l31 = lane & 31;
  const int hk = (lane >> 5) * 8;       // k-subchunk within 16
  const float* qb = qo + (size_t)b * 65536;
  const float* kb = ko + (size_t)b * 65536;
  const ushort* vp = vws + (size_t)b * 524288;
  float* ab = attn + (size_t)b * 16777216;

  float qv[8][16];
#pragma unroll
  for (int r = 0; r < 8; r++)
#pragma unroll
    for (int d = 0; d < 16; d++)
      qv[r][d] = qb[d * 4096 + nbase + r];

  // ---- Phase 1: denominator ----
  float sume[8];
#pragma unroll
  for (int r = 0; r < 8; r++) sume[r] = 0.f;
  for (int m0 = 0; m0 < M; m0 += 64) {
    float kreg[16];
#pragma unroll
    for (int d = 0; d < 16; d++) kreg[d] = kb[d * 4096 + m0 + lane];
#pragma unroll
    for (int r = 0; r < 8; r++) {
      float e = 0.f;
#pragma unroll
      for (int d = 0; d < 16; d++) e += qv[r][d] * kreg[d];
      sume[r] += __expf(e);
    }
  }
  float inv[8];
#pragma unroll
  for (int r = 0; r < 8; r++) {
    float s = sume[r];
#pragma unroll
    for (int off = 32; off > 0; off >>= 1) s += __shfl_xor(s, off, 64);
    inv[r] = 1.0f / s;
  }

  // ---- Phase 2: attn write + PV accumulate ----
  float16 acc;
#pragma unroll
  for (int i = 0; i < 16; i++) acc[i] = 0.f;

  for (int s = 0; s < S; s++) {
    const int m0 = s * 64;
    ushort* Pb = Ps[s & 1];
    float kreg[16];
#pragma unroll
    for (int d = 0; d < 16; d++) kreg[d] = kb[d * 4096 + m0 + lane];
#pragma unroll
    for (int r = 0; r < 8; r++) {
      float e = 0.f;
#pragma unroll
      for (int d = 0; d < 16; d++) e += qv[r][d] * kreg[d];
      float p = __expf(e) * inv[r];
      ab[(size_t)(nbase + r) * 4096 + m0 + lane] = p;
      Pb[(wave * 8 + r) * 72 + lane] = f2bf(p);
    }
    __syncthreads();
    const ushort* vrow = vp + (size_t)(wave * 32 + l31) * 4096 + m0 + hk;
#pragma unroll
    for (int kk = 0; kk < 4; kk++) {
      short8 a  = *(const short8*)(vrow + kk * 16);          // V[c][m-chunk]
      short8 bf = *(const short8*)(Pb + l31 * 72 + kk * 16 + hk); // P[n][m-chunk]
      acc = __builtin_amdgcn_mfma_f32_32x32x16_bf16(a, bf, acc, 0, 0, 0);
    }
    // buf (s&1) is only rewritten at s+2, after the s+1 barrier -> safe.
  }

  // ---- Epilogue: zero-fill masked attn region ----
  const int Z4 = (4096 - M) >> 2;
#pragma unroll
  for (int r = 0; r < 8; r++) {
    float4* dst = (float4*)(ab + (size_t)(nbase + r) * 4096 + M);
    for (int i4 = lane; i4 < Z4; i4 += 64)
      dst[i4] = make_float4(0.f, 0.f, 0.f, 0.f);
  }

  // ---- Epilogue: out = gamma * acc + x ----
  const float gamma = g[0];
#pragma unroll
  for (int reg = 0; reg < 16; reg++) {
    int row = (reg & 3) + 8 * (reg >> 2) + 4 * (lane >> 5);  // C/D row map
    int c = wave * 32 + row;
    int n = nblk + l31;                                      // C/D col = lane&31
    size_t off = (size_t)b * 524288 + (size_t)c * 4096 + n;
    out[off] = gamma * acc[reg] + x[off];
  }
}

extern "C" void kernel_launch(void* const* d_in, const int* in_sizes, int n_in,
                              void* d_out, int out_size, void* d_ws, size_t ws_size,
                              hipStream_t stream) {
  const float* x  = (const float*)d_in[0];
  const float* wq = (const float*)d_in[1];
  const float* bq = (const float*)d_in[2];
  const float* wk = (const float*)d_in[3];
  const float* bk = (const float*)d_in[4];
  const float* wv = (const float*)d_in[5];
  const float* bv = (const float*)d_in[6];
  const float* gm = (const float*)d_in[7];
  float* out  = (float*)d_out;
  float* attn = out + 2097152;           // output 1: attention [4][4096][4096]
  float* qws = (float*)d_ws;             // fp32 [4][16][4096]
  float* kws = qws + 262144;             // fp32 [4][16][4096]
  ushort* vws = (ushort*)(qws + 524288); // bf16 [4][128][4096]

  qkv_kernel<<<dim3(64, 4), 512, 0, stream>>>(x, wq, bq, wk, bk, wv, bv, qws, kws, vws);
  fused_attn_kernel<<<dim3(512), 256, 0, stream>>>(qws, kws, vws, x, gm, attn, out);
}

// Round 4
// 356.603 us; speedup vs baseline: 1.9603x; 1.2293x over previous
//
#include <hip/hip_runtime.h>
#include <hip/hip_bf16.h>

// Problem constants: B=4, C=128, Cq=16, W=H=64, N=4096.
// ws layout (ushort): qT bf16 [4][4096][16] @0, kT bf16 [4][4096][16] @262144,
//                     v  bf16 [4][128][4096] @524288
// d_out: out[4][128][4096] fp32, then attention[4][4096][4096] fp32

typedef __attribute__((ext_vector_type(8))) short short8;
typedef __attribute__((ext_vector_type(16))) float float16;

__device__ __forceinline__ ushort f2bf(float f) {
  union { float f; uint u; } v; v.f = f;
  return (ushort)((v.u + 0x7FFFu + ((v.u >> 16) & 1u)) >> 16);  // RNE
}

// ---------------- Kernel 1: QKV projections ----------------
// grid (64 n-tiles, 4 b), 512 threads. q,k written as bf16 TRANSPOSED
// ([position][16 d], contiguous d) so the fused kernel can load MFMA A/B
// fragments as single short8s. V written bf16 [c][m] as before.
__global__ __launch_bounds__(512, 2) void qkv_kernel(
    const float* __restrict__ x,
    const float* __restrict__ wq, const float* __restrict__ bq,
    const float* __restrict__ wk, const float* __restrict__ bk,
    const float* __restrict__ wv, const float* __restrict__ bv,
    ushort* __restrict__ qT, ushort* __restrict__ kT, ushort* __restrict__ vo) {
  __shared__ float xs[128 * 64];
  const int nt = blockIdx.x, b = blockIdx.y;
  const int n0 = nt * 64;
  const float* xb = x + (size_t)b * 524288 + n0;
  for (int idx = threadIdx.x; idx < 8192; idx += 512) {
    int c = idx >> 6, n = idx & 63;
    xs[idx] = xb[(size_t)c * 4096 + n];
  }
  __syncthreads();
  const int n = threadIdx.x & 63;
  const int og = __builtin_amdgcn_readfirstlane((int)(threadIdx.x >> 6)); // 0..7
  float acc[20];
#pragma unroll
  for (int i = 0; i < 20; i++) {
    int o = og + 8 * i;
    acc[i] = (i < 2) ? bq[o] : (i < 4) ? bk[o - 16] : bv[o - 32];
  }
#pragma unroll 4
  for (int c = 0; c < 128; c++) {
    float xr = xs[c * 64 + n];
#pragma unroll
    for (int i = 0; i < 20; i++) {
      int o = og + 8 * i;
      const float* wr = (i < 2) ? (wq + o * 128)
                      : (i < 4) ? (wk + (o - 16) * 128)
                                : (wv + (o - 32) * 128);
      acc[i] += wr[c] * xr;
    }
  }
  const size_t pos = (size_t)b * 4096 + n0 + n;  // global position index
#pragma unroll
  for (int i = 0; i < 20; i++) {
    int o = og + 8 * i;
    if (i < 2)      qT[pos * 16 + o]      = f2bf(acc[i]);
    else if (i < 4) kT[pos * 16 + o - 16] = f2bf(acc[i]);
    else vo[(size_t)b * 524288 + (size_t)(o - 32) * 4096 + n0 + n] = f2bf(acc[i]);
  }
}

// ---------------- Kernel 2: fused energy(MFMA) + softmax + attn + PV ---------
// 512 blocks x 256 thr (4 waves). Block = (b, rb, half): 32 n-rows,
// M=(rb+1)*64 valid cols, S=M/64 strips. rb=(u<32)?u:95-u load-balances pairs.
// Energy tile E[32n][32m] = one mfma_32x32x16_bf16 (A=q-frag, B=k-frag, both
// loaded as contiguous short8 from the transposed bf16 ws arrays).
// Phase 1: rowwise sum(exp(E)) in C-layout regs; reduce over cols via 5
//   shuffles; cross-wave partials through LDS red[32][4].
// Phase 2 per super-step (4 strips): wave w computes E for strip s0+w,
//   writes p=exp(E)*inv to attn (fp32, from C-regs) and bf16 p to LDS slot w;
//   barrier; all waves run PV MFMA (identical layout to verified R3 kernel)
//   over the 4 slots, c-quadrant = wave. Epilogue: zero-fill + out=g*acc+x.
__global__ __launch_bounds__(256, 2) void fused_attn_kernel(
    const ushort* __restrict__ qT, const ushort* __restrict__ kT,
    const ushort* __restrict__ vws, const float* __restrict__ x,
    const float* __restrict__ g,
    float* __restrict__ attn, float* __restrict__ out) {
  __shared__ __align__(16) ushort Pt[4][32 * 72];
  __shared__ __align__(16) float red[32][4];
  const int bx = blockIdx.x;            // 0..511
  const int b = bx & 3;
  const int v_ = bx >> 2;               // 0..127
  const int half = v_ & 1;
  const int u = v_ >> 1;                // 0..63
  const int rb = (u < 32) ? u : 95 - u; // CU-mate load balancing
  const int S = rb + 1;
  const int lane = threadIdx.x & 63;
  const int w = __builtin_amdgcn_readfirstlane((int)(threadIdx.x >> 6));
  const int nblk = rb * 64 + half * 32;
  const int l31 = lane & 31;
  const int h = lane >> 5;
  const int hk = h * 8;
  const ushort* qb = qT + (size_t)b * 65536;
  const ushort* kb = kT + (size_t)b * 65536;
  const ushort* vp = vws + (size_t)b * 524288;
  float* ab = attn + (size_t)b * 16777216;

  // q A-fragment for this block's 32 rows: A[n=l31][d=hk..hk+7] — 4 VGPRs.
  const short8 qa = *(const short8*)(qb + (size_t)(nblk + l31) * 16 + hk);

  float16 zero16;
#pragma unroll
  for (int i = 0; i < 16; i++) zero16[i] = 0.f;

  // ---- Phase 1: denominators ----
  float sume[16];
#pragma unroll
  for (int i = 0; i < 16; i++) sume[i] = 0.f;
  for (int s = w; s < S; s += 4) {
    const int m0 = s * 64;
#pragma unroll
    for (int mh = 0; mh < 2; mh++) {
      short8 kf = *(const short8*)(kb + (size_t)(m0 + mh * 32 + l31) * 16 + hk);
      float16 e = __builtin_amdgcn_mfma_f32_32x32x16_bf16(qa, kf, zero16, 0, 0, 0);
#pragma unroll
      for (int r = 0; r < 16; r++) sume[r] += __expf(e[r]);
    }
  }
#pragma unroll
  for (int r = 0; r < 16; r++) {
#pragma unroll
    for (int off = 1; off <= 16; off <<= 1)
      sume[r] += __shfl_xor(sume[r], off, 64);  // sum over 32 cols (l31 group)
  }
  if (l31 == 0) {
#pragma unroll
    for (int r = 0; r < 16; r++) {
      int row = (r & 3) + 8 * (r >> 2) + 4 * h;
      red[row][w] = sume[r];
    }
  }
  __syncthreads();
  float inv[16];
#pragma unroll
  for (int r = 0; r < 16; r++) {
    int row = (r & 3) + 8 * (r >> 2) + 4 * h;
    float4 p4 = *(const float4*)&red[row][0];
    inv[r] = 1.0f / (p4.x + p4.y + p4.z + p4.w);
  }

  // ---- Phase 2: attn write + PV accumulate ----
  float16 acc = zero16;
  for (int s0 = 0; s0 < S; s0 += 4) {
    const int sl = (S - s0 < 4) ? (S - s0) : 4;
    if (w < sl) {
      const int m0 = (s0 + w) * 64;
      ushort* Pb = &Pt[w][0];
#pragma unroll
      for (int mh = 0; mh < 2; mh++) {
        short8 kf = *(const short8*)(kb + (size_t)(m0 + mh * 32 + l31) * 16 + hk);
        float16 e = __builtin_amdgcn_mfma_f32_32x32x16_bf16(qa, kf, zero16, 0, 0, 0);
#pragma unroll
        for (int r = 0; r < 16; r++) {
          int row = (r & 3) + 8 * (r >> 2) + 4 * h;
          float p = __expf(e[r]) * inv[r];
          ab[(size_t)(nblk + row) * 4096 + m0 + mh * 32 + l31] = p;
          Pb[row * 72 + mh * 32 + l31] = f2bf(p);
        }
      }
    }
    __syncthreads();
    for (int ss = 0; ss < sl; ss++) {
      const int m0 = (s0 + ss) * 64;
      const ushort* vrow = vp + (size_t)(w * 32 + l31) * 4096 + m0 + hk;
      const ushort* Pr = &Pt[ss][l31 * 72 + hk];
#pragma unroll
      for (int kk = 0; kk < 4; kk++) {
        short8 a  = *(const short8*)(vrow + kk * 16);
        short8 bf = *(const short8*)(Pr + kk * 16);
        acc = __builtin_amdgcn_mfma_f32_32x32x16_bf16(a, bf, acc, 0, 0, 0);
      }
    }
    __syncthreads();
  }

  // ---- Epilogue: zero-fill masked attn region (wave w: rows w*8..w*8+7) ----
  const int M = S * 64;
  const int Z4 = (4096 - M) >> 2;
  const float4 z = make_float4(0.f, 0.f, 0.f, 0.f);
#pragma unroll
  for (int r = 0; r < 8; r++) {
    float4* dst = (float4*)(ab + (size_t)(nblk + w * 8 + r) * 4096 + M);
    for (int i4 = lane; i4 < Z4; i4 += 64) dst[i4] = z;
  }

  // ---- Epilogue: out = gamma * acc + x ----
  const float gamma = g[0];
#pragma unroll
  for (int reg = 0; reg < 16; reg++) {
    int row = (reg & 3) + 8 * (reg >> 2) + 4 * h;  // C/D row map
    int c = w * 32 + row;
    int n = nblk + l31;                            // C/D col = lane&31
    size_t off = (size_t)b * 524288 + (size_t)c * 4096 + n;
    out[off] = gamma * acc[reg] + x[off];
  }
}

extern "C" void kernel_launch(void* const* d_in, const int* in_sizes, int n_in,
                              void* d_out, int out_size, void* d_ws, size_t ws_size,
                              hipStream_t stream) {
  const float* x  = (const float*)d_in[0];
  const float* wq = (const float*)d_in[1];
  const float* bq = (const float*)d_in[2];
  const float* wk = (const float*)d_in[3];
  const float* bk = (const float*)d_in[4];
  const float* wv = (const float*)d_in[5];
  const float* bv = (const float*)d_in[6];
  const float* gm = (const float*)d_in[7];
  float* out  = (float*)d_out;
  float* attn = out + 2097152;            // output 1: attention [4][4096][4096]
  ushort* qTw = (ushort*)d_ws;            // bf16 [4][4096][16]
  ushort* kTw = qTw + 262144;             // bf16 [4][4096][16]
  ushort* vws = qTw + 524288;             // bf16 [4][128][4096]

  qkv_kernel<<<dim3(64, 4), 512, 0, stream>>>(x, wq, bq, wk, bk, wv, bv, qTw, kTw, vws);
  fused_attn_kernel<<<dim3(512), 256, 0, stream>>>(qTw, kTw, vws, x, gm, attn, out);
}